// Round 7
// baseline (246.278 us; speedup 1.0000x reference)
//
#include <hip/hip_runtime.h>
#include <hip/hip_bf16.h>

// GraphConvolution: out = relu( (W@x + b) @ adj^T + x ), B=4096, C=256, N=25.
// R12 = R11 with the double-x-read removed (R11: FETCH 56->165MB because the
// residual re-read x from global at store time, also exposing an HBM latency
// chain per phase).
//  - residual now comes from the bf16 xsT tile already in LDS, folded in as
//    MFMA2's C-initializer (4x ds_read_b64/thread; rows>=25 are the zeroed
//    region). MFMA2 computes s@adjT + bias*aS + x in one pass.
//  - relu applied at outS staging; global store is a pure outS->out dwordx4
//    copy (no dependent global load at phase end).
//  - precision: bf16-rounded residual adds <=~0.01 abs error; R9 passed at
//    absmax 0.172 so threshold headroom is ample.
// Everything else identical to R11 (verified): single barrier/phase, xsT
// bf16 dbuf staged via short reg window, ss wave-private aliasing outS,
// bias as pseudo-channel n=25, 32x32x16 MFMA, LDS 61440 B -> 2 blocks/CU.

#define BATCH 4096
#define C 256
#define N 25
#define NB 8
#define XW 6400          // floats per batch tile (256*25)
#define CSTRT 264        // xsT row stride in bf16 (528 B, 16B-mult)
#define SSTR 40          // ss row stride in bf16 (80 B, 16B-mult)

typedef __bf16 bf16x8 __attribute__((ext_vector_type(8)));
typedef __bf16 bf16x4 __attribute__((ext_vector_type(4)));
typedef float f32x16 __attribute__((ext_vector_type(16)));

// ---- prep: Wshuf[(wv*16+kt)*64+l] = 32x32x16 A-frag of W for wave wv ----
// lane l holds A[row = wv*32 + (l&31)][k = kt*16 + (l>>5)*8 + j], j=0..7
__global__ void prep_kernel(const float* __restrict__ W, const float* __restrict__ adj,
                            bf16x8* __restrict__ Wshuf, float* __restrict__ adjS) {
    int i = blockIdx.x * 256 + threadIdx.x;       // 8192 = 128 frags x 64 lanes
    int f = i >> 6, l = i & 63;
    int wvp = f >> 4, kt = f & 15;
    int row = wvp * 32 + (l & 31);
    int cb  = kt * 16 + ((l >> 5) << 3);
    bf16x8 v;
    #pragma unroll
    for (int j = 0; j < 8; ++j) v[j] = (__bf16)W[row * C + cb + j];
    Wshuf[i] = v;
    if (blockIdx.x == 0 && threadIdx.x < 32) {
        float s = 0.f;
        if (threadIdx.x < N)
            for (int n = 0; n < N; ++n) s += adj[threadIdx.x * N + n];
        adjS[threadIdx.x] = s;
    }
}

__global__ __launch_bounds__(512, 4) void gcn_kernel(
    const float* __restrict__ x, const float* __restrict__ adj,
    const float* __restrict__ bias, const float* __restrict__ adjSg,
    const bf16x8* __restrict__ Wshuf, float* __restrict__ out)
{
    __shared__ __align__(16) __bf16 xsT[2][32 * CSTRT]; // 33792 B, x^T bf16 dbuf
    __shared__ __align__(16) float  outS[XW];           // 25600 B; ss aliases slices
    __shared__ __align__(16) __bf16 adjTf[2 * 64 * 8];  //  2048 B, adjT B-frags

    const int tid = threadIdx.x;                   // 0..511
    const int wv = tid >> 6, lane = tid & 63;      // 8 waves
    const int l31 = lane & 31, lh = lane >> 5;
    const int o0 = wv * 32;                        // wave's 32 output rows
    const int b0 = blockIdx.x * NB;

    // wave-private s scratch: 32 rows x SSTR bf16 = 2560 B inside own outS slice
    __bf16* const ssw = (__bf16*)((char*)outS + wv * 3200);

    // ---- one-time init ----
    // zero xsT rows N..31 (both buffers): deterministic zeros for discarded
    // MFMA columns AND for the m>=25 residual lanes.
    for (int e = tid; e < 2 * (32 - N) * CSTRT; e += 512) {
        int buf = e / ((32 - N) * CSTRT), r = e % ((32 - N) * CSTRT);
        xsT[buf][(N + r / CSTRT) * CSTRT + (r % CSTRT)] = (__bf16)0.f;
    }
    // adjT B-frags: lane l holds B[n = kt*16+(l>>5)*8+j][m = l&31];
    // n<25 -> adj[m][n]; n==25 -> aS[m] (bias channel); else 0. m>=25 -> 0.
    if (tid < 128) {
        int kt = tid >> 6, l = tid & 63;
        int m = l & 31, nb = kt * 16 + ((l >> 5) << 3);
        bf16x8 v;
        #pragma unroll
        for (int j = 0; j < 8; ++j) {
            int n = nb + j;
            float val = 0.f;
            if (m < N) { if (n < N) val = adj[m * N + n]; else if (n == N) val = adjSg[m]; }
            v[j] = (__bf16)val;
        }
        *(bf16x8*)&adjTf[(kt * 64 + l) * 8] = v;
    }

    bf16x8 af[16];   // 64 regs: W A-frags, coalesced 1KB loads
    #pragma unroll
    for (int kt = 0; kt < 16; ++kt)
        af[kt] = Wshuf[(wv * 16 + kt) * 64 + lane];

    const float biasL = bias[o0 + l31];   // used by lanes<32 for ss bias column

    // ---- prologue: stage x[b0] transposed into xsT[0] ----
    {
        const float4* xb4 = (const float4*)(x + (size_t)b0 * XW);
        #pragma unroll
        for (int q = 0; q < 4; ++q)
            if (q < 3 || lane < 8) {
                int i4 = wv * 200 + q * 64 + lane;
                float4 v = xb4[i4];
                int e = i4 * 4;
                int c = e / N, n = e - c * N;
                float fv[4] = {v.x, v.y, v.z, v.w};
                #pragma unroll
                for (int j = 0; j < 4; ++j) {
                    xsT[0][n * CSTRT + c] = (__bf16)fv[j];
                    ++n; if (n == N) { n = 0; ++c; }
                }
            }
    }
    __syncthreads();   // adjTf + xsT[0] + zero-rows visible (full drain, once)

    #pragma unroll 1
    for (int bi = 0; bi < NB; ++bi) {
        const int p = bi & 1;
        const __bf16* xr = xsT[p];
        float* outb = out + (size_t)(b0 + bi) * XW;
        const bool pf = (bi + 1 < NB);

        // ---- A) stage loads for x[bi+1] (short reg window; writes after GEMM1)
        float4 sv[4];
        if (pf) {
            const float4* xn4 = (const float4*)(x + (size_t)(b0 + bi + 1) * XW);
            #pragma unroll
            for (int q = 0; q < 4; ++q)
                if (q < 3 || lane < 8) sv[q] = xn4[wv * 200 + q * 64 + lane];
        }

        // ---- B) GEMM1: s[o][n] = sum_c W[o][c] x[c][n], 16 MFMA 32x32x16 ----
        f32x16 acc = (f32x16)0.f;
        #pragma unroll
        for (int kt = 0; kt < 16; ++kt) {
            bf16x8 xf = *(const bf16x8*)&xr[l31 * CSTRT + kt * 16 + lh * 8];
            acc = __builtin_amdgcn_mfma_f32_32x32x16_bf16(af[kt], xf, acc, 0, 0, 0);
        }

        // ---- C) s -> wave-private ss (cols >=25 zeroed; bias col rewritten) ----
        #pragma unroll
        for (int r = 0; r < 16; ++r) {
            int o = (r & 3) + 8 * (r >> 2) + 4 * lh;
            ssw[o * SSTR + l31] = (__bf16)((l31 < N) ? acc[r] : 0.f);
        }
        if (lane < 32) ssw[lane * SSTR + N] = (__bf16)biasL;   // n=25 = bias channel

        // ---- D) residual C-init from xsT (bf16, LDS; no global re-read):
        //      acc[r] = x[channel o0+o_r][node m=l31]; o_r = (r&3)+8*(r>>2)+4*lh
        //      -> 4 groups of 4 consecutive channels = 4x ds_read_b64.
        //      l31>=25 lanes read the zeroed rows (cols discarded anyway).
        #pragma unroll
        for (int g = 0; g < 4; ++g) {
            bf16x4 xv = *(const bf16x4*)&xr[l31 * CSTRT + o0 + g * 8 + 4 * lh];
            #pragma unroll
            for (int i = 0; i < 4; ++i) acc[g * 4 + i] = (float)xv[i];
        }

        // ---- D') MFMA2: out[o][m] = x[o][m] + sum_n s[o][n] adjT[n][m] ----
        #pragma unroll
        for (int kt = 0; kt < 2; ++kt) {
            bf16x8 sA = *(const bf16x8*)&ssw[l31 * SSTR + kt * 16 + lh * 8];
            bf16x8 aB = *(const bf16x8*)&adjTf[(kt * 64 + lane) * 8];
            acc = __builtin_amdgcn_mfma_f32_32x32x16_bf16(sA, aB, acc, 0, 0, 0);
        }

        // ---- E) relu + stage outS (wave-private slice) ----
        #pragma unroll
        for (int r = 0; r < 16; ++r) {
            int o = (r & 3) + 8 * (r >> 2) + 4 * lh;
            if (l31 < N) {
                float v = acc[r];
                outS[(o0 + o) * N + l31] = v > 0.f ? v : 0.f;
            }
        }

        // ---- F) write staged x[bi+1] transposed into xsT[p^1] ----
        if (pf) {
            #pragma unroll
            for (int q = 0; q < 4; ++q)
                if (q < 3 || lane < 8) {
                    int e = (wv * 200 + q * 64 + lane) * 4;
                    int c = e / N, n = e - c * N;
                    float fv[4] = {sv[q].x, sv[q].y, sv[q].z, sv[q].w};
                    #pragma unroll
                    for (int j = 0; j < 4; ++j) {
                        xsT[p ^ 1][n * CSTRT + c] = (__bf16)fv[j];
                        ++n; if (n == N) { n = 0; ++c; }
                    }
                }
        }

        // ---- G) pure copy: outS slice -> out, coalesced dwordx4 ----
        #pragma unroll
        for (int q = 0; q < 4; ++q)
            if (q < 3 || lane < 8) {
                int i4 = wv * 200 + q * 64 + lane;
                ((float4*)outb)[i4] = ((const float4*)outS)[i4];
            }

        // ---- H) single phase barrier: xsT[p^1] visible; xsT[p]/outS reads
        //      drained. LDS drain only -- global stores stay in flight.
        asm volatile("s_waitcnt lgkmcnt(0)\n\ts_barrier" ::: "memory");
    }
}

extern "C" void kernel_launch(void* const* d_in, const int* in_sizes, int n_in,
                              void* d_out, int out_size, void* d_ws, size_t ws_size,
                              hipStream_t stream) {
    (void)in_sizes; (void)n_in; (void)out_size; (void)ws_size;
    const float* x    = (const float*)d_in[0];   // [4096, 256, 25]
    const float* adj  = (const float*)d_in[1];   // [25, 25]
    const float* W    = (const float*)d_in[2];   // [256, 256]
    const float* bias = (const float*)d_in[3];   // [256]
    float* out = (float*)d_out;

    unsigned char* ws = (unsigned char*)d_ws;
    bf16x8* Wshuf = (bf16x8*)ws;                 // 131072 B
    float*  adjS  = (float*)(ws + 131072);       // 128 B

    prep_kernel<<<32, 256, 0, stream>>>(W, adj, Wshuf, adjS);
    gcn_kernel<<<BATCH / NB, 512, 0, stream>>>(x, adj, bias, adjS, Wshuf, out);
}